// Round 10
// baseline (2096.178 us; speedup 1.0000x reference)
//
#include <hip/hip_runtime.h>

#define B_    8
#define N_    8192
#define M_    2000
#define K_    16
#define C1_   128
#define C2_   256
#define OUT_  100
#define SUBP_ 2048   // padded per-batch pitch for subsampled points (KNN2 candidates)

// ---------------------------------------------------------------- prep: coords -> float4(x,y,z,|p|^2); pad sub4 sentinels
__global__ __launch_bounds__(256) void prep_kernel(const float* __restrict__ x,
                                                   float4* __restrict__ coords4,
                                                   float4* __restrict__ sub4) {
    int i = blockIdx.x * 256 + threadIdx.x;
    if (i < B_ * N_) {
        float xx = x[i*3+0], yy = x[i*3+1], zz = x[i*3+2];
        float ss = fmaf(zz, zz, fmaf(yy, yy, xx*xx));   // ((x^2+y^2)+z^2)
        coords4[i] = make_float4(xx, yy, zz, ss);
    }
    if (i < B_ * (SUBP_ - M_)) {   // sentinel pads: huge distance, never selected
        int b = i / (SUBP_ - M_), j = i % (SUBP_ - M_);
        sub4[b*SUBP_ + M_ + j] = make_float4(1e15f, 1e15f, 1e15f, 3e30f);
    }
}

// ---------------------------------------------------------------- FPS v10: 16-way chunks, 4 waves/SIMD, lane-parallel combine
// v9 (fps 1376us, best) proved: wave-bbox prune + in-loop argmax. v10 refines:
//  - 1024T, 16 waves, 8 pts/lane: chunk diameter ~0.4 (vs octant 0.5) -> smaller
//    active set AND each active wave runs half the update loop (~120 vs ~210 insts)
//  - wave->SIMD = w&3 puts chunks {s,s+4,s+8,s+12} (4 distinct xy-quadrants per
//    Morton bits 2-3) on one SIMD -> ~1 active wave/SIMD; 4 waves hide the tail
//  - combine over 16 keys: lane-parallel (lane reads key[lane&15], 4-stage
//    row_shr DPP u64 reduce, read lane 15) ~25 insts vs 53-inst umax64 tree
// Prune/tie semantics byte-identical to v9 (margin 0.99999, strict-> argmax).
#define FPS_T 1024
#define FPS_P 8    // points per thread: 1024*8 = 8192
#define FPS_W 16   // waves

__device__ __forceinline__ unsigned long long umax64(unsigned long long a, unsigned long long b) {
    return a > b ? a : b;
}

// one stage of wave/row-max on a u64 key via DPP on both halves (identity 0: keys non-negative)
template<int CTRL>
__device__ __forceinline__ unsigned long long dpp_max_u64(unsigned long long v) {
    int lo = __builtin_amdgcn_update_dpp(0, (int)(unsigned)(v & 0xFFFFFFFFull), CTRL, 0xF, 0xF, true);
    int hi = __builtin_amdgcn_update_dpp(0, (int)(v >> 32),                     CTRL, 0xF, 0xF, true);
    unsigned long long o = ((unsigned long long)(unsigned)hi << 32) | (unsigned)lo;
    return umax64(v, o);
}

__device__ __forceinline__ int spread3(int v) {   // 3 bits -> bits 0,3,6
    return (v & 1) | ((v & 2) << 2) | ((v & 4) << 4);
}

__global__ __launch_bounds__(FPS_T, 1) void fps_kernel(const float4* __restrict__ coords4,
                                                       float4* __restrict__ sub4) {
    int b = blockIdx.x;
    int t = threadIdx.x;
    int w = t >> 6, lane = t & 63;
    const float4* C = coords4 + b * N_;

    __shared__ float4 Clds[N_];                              // 128 KB coords mirror (by ORIGINAL index)
    __shared__ unsigned short sidx[N_];                      // 16 KB sorted->original index map
    __shared__ unsigned int hist[512];                       // counting-sort histogram / cursors
    __shared__ __align__(16) unsigned long long wkey[2][FPS_W];  // per-wave keys, parity double-buffered

    if (t < 512) hist[t] = 0u;
    __syncthreads();

    // ---- phase A: load coords (coalesced), mirror to LDS, Morton-cell histogram
    int cellv[FPS_P];
#pragma unroll
    for (int j = 0; j < FPS_P; ++j) {
        int i = t + j*FPS_T;
        float4 p = C[i];
        Clds[i] = p;
        int cx = (int)(p.x * 8.0f); cx = cx < 0 ? 0 : (cx > 7 ? 7 : cx);
        int cy = (int)(p.y * 8.0f); cy = cy < 0 ? 0 : (cy > 7 ? 7 : cy);
        int cz = (int)(p.z * 8.0f); cz = cz < 0 ? 0 : (cz > 7 ? 7 : cz);
        int cell = (spread3(cx) << 2) | (spread3(cy) << 1) | spread3(cz);   // 9-bit Morton
        cellv[j] = cell;
        atomicAdd(&hist[cell], 1u);
    }
    __syncthreads();

    // ---- phase B: exclusive prefix sum of hist[512] (wave 0)
    if (w == 0) {
        unsigned loc[8], tot = 0u;
#pragma unroll
        for (int c2 = 0; c2 < 8; ++c2) { loc[c2] = hist[lane*8 + c2]; tot += loc[c2]; }
        unsigned pre = tot;
#pragma unroll
        for (int d = 1; d < 64; d <<= 1) {
            unsigned o = __shfl_up(pre, d, 64);
            if (lane >= (unsigned)d) pre += o;
        }
        unsigned run = pre - tot;                            // exclusive base for this lane's 8 cells
#pragma unroll
        for (int c2 = 0; c2 < 8; ++c2) { unsigned v = loc[c2]; hist[lane*8 + c2] = run; run += v; }
    }
    __syncthreads();

    // ---- phase C: scatter original indices into Morton order
#pragma unroll
    for (int j = 0; j < FPS_P; ++j) {
        int i = t + j*FPS_T;
        unsigned pos = atomicAdd(&hist[cellv[j]], 1u);
        sidx[pos] = (unsigned short)i;
    }
    __syncthreads();

    // ---- phase D: wave w owns sorted chunk [w*512,(w+1)*512); lane owns 8 contiguous
    int sbase = w*512 + lane*FPS_P;
    float px_[FPS_P], py_[FPS_P], pz_[FPS_P], mind[FPS_P];
    unsigned inv_[FPS_P];
    float wx0 =  1e30f, wy0 =  1e30f, wz0 =  1e30f;
    float wx1 = -1e30f, wy1 = -1e30f, wz1 = -1e30f;
#pragma unroll
    for (int j = 0; j < FPS_P; ++j) {
        int o = (int)sidx[sbase + j];
        float4 p = Clds[o];
        px_[j] = p.x; py_[j] = p.y; pz_[j] = p.z;
        mind[j] = 1e30f;
        inv_[j] = 0xFFFFFFFFu - (unsigned)o;                 // tie -> smaller ORIGINAL index
        wx0 = fminf(wx0, p.x); wx1 = fmaxf(wx1, p.x);
        wy0 = fminf(wy0, p.y); wy1 = fmaxf(wy1, p.y);
        wz0 = fminf(wz0, p.z); wz1 = fmaxf(wz1, p.z);
    }
    // wave bbox: reduce lane bboxes across the wave (one-time)
    for (int s = 1; s < 64; s <<= 1) {
        wx0 = fminf(wx0, __shfl_xor(wx0, s, 64)); wx1 = fmaxf(wx1, __shfl_xor(wx1, s, 64));
        wy0 = fminf(wy0, __shfl_xor(wy0, s, 64)); wy1 = fmaxf(wy1, __shfl_xor(wy1, s, 64));
        wz0 = fminf(wz0, __shfl_xor(wz0, s, 64)); wz1 = fmaxf(wz1, __shfl_xor(wz1, s, 64));
    }

    float4 P0 = Clds[0];                                     // first pick = original index 0
    if (t == 0) sub4[b*SUBP_] = P0;
    float Px = P0.x, Py = P0.y, Pz = P0.z;
    unsigned long long wk = ((unsigned long long)__float_as_uint(1e30f) << 32);  // cached wave key
    float wmaxf = 1e30f;                                     // cached wave-max mind

    for (int i = 1; i < M_; ++i) {
        // wave-level prune: dmin^2(P, wavebbox) vs cached wave max (skip => bit-exact no-op)
        float qx = fminf(fmaxf(Px, wx0), wx1);
        float qy = fminf(fmaxf(Py, wy0), wy1);
        float qz = fminf(fmaxf(Pz, wz0), wz1);
        float ddx = Px - qx, ddy = Py - qy, ddz = Pz - qz;
        float dmin2 = fmaf(ddz, ddz, fmaf(ddy, ddy, ddx*ddx));
        if (dmin2 * 0.99999f < wmaxf) {                      // ACTIVE: full recompute (all lanes)
            float runmax = -3.4e38f;
            unsigned ib = 0u;
#pragma unroll
            for (int j = 0; j < FPS_P; ++j) {
                float dx = px_[j] - Px, dy = py_[j] - Py, dz = pz_[j] - Pz;
                float d = fmaf(dz, dz, fmaf(dy, dy, dx*dx)); // direct form matches reference FPS
                float m = fminf(mind[j], d);
                mind[j] = m;
                ib = (m > runmax) ? inv_[j] : ib;            // strict >: first max kept (= v9 ties)
                runmax = fmaxf(runmax, m);
            }
            unsigned long long best = ((unsigned long long)__float_as_uint(runmax) << 32)
                                    | (unsigned long long)ib;
            // wave max into lane 63: row_shr 1/2/4/8 then row_bcast 15/31 (all VALU)
            best = dpp_max_u64<0x111>(best);
            best = dpp_max_u64<0x112>(best);
            best = dpp_max_u64<0x114>(best);
            best = dpp_max_u64<0x118>(best);
            best = dpp_max_u64<0x142>(best);
            best = dpp_max_u64<0x143>(best);
            wk = best;
            wmaxf = __uint_as_float((unsigned)__builtin_amdgcn_readlane((int)(unsigned)(wk >> 32), 63));
        }
        if (lane == 63) wkey[i & 1][w] = wk;
        __syncthreads();
        // ---- lane-parallel combine: lane reads key[lane&15], 4-stage row reduce, lane15 has winner
        unsigned long long kk = wkey[i & 1][lane & 15];
        kk = dpp_max_u64<0x111>(kk);
        kk = dpp_max_u64<0x112>(kk);
        kk = dpp_max_u64<0x114>(kk);
        kk = dpp_max_u64<0x118>(kk);
        unsigned lastinv = (unsigned)__builtin_amdgcn_readlane((int)(unsigned)(kk & 0xFFFFFFFFull), 15);
        int last = (int)(0xFFFFFFFFu - lastinv);
        float4 P4 = Clds[last];                              // broadcast LDS read (w = |p|^2 intact)
        Px = P4.x; Py = P4.y; Pz = P4.z;
        if (t == 0) sub4[b*SUBP_ + i] = P4;
    }
}

// ---------------------------------------------------------------- KNN: 1 wave per query, exact top-16 (set semantics)
// Pass 1: branchless lane-local sorted-16 of values only (15 CE bubble per candidate).
// Merge:  k-way merge of 64 sorted heads -> T = exact 16th smallest distance.
// Pass 2: ballot-collect indices with d<T, then earliest-index ties d==T (matches lax.top_k stability).
template<int NCH, int PITCH>
__global__ __launch_bounds__(256) void knn_kernel(const float4* __restrict__ cand,
                                                  const float4* __restrict__ qarr,
                                                  int* __restrict__ outIdx) {
    int lane = threadIdx.x & 63;
    int q = blockIdx.x * 4 + (threadIdx.x >> 6);
    int b = q / M_, m = q % M_;
    const float4* Cb = cand + b * PITCH;
    float4 Q = qarr[b * SUBP_ + m];

    float v[16];
#pragma unroll
    for (int tt = 0; tt < 16; ++tt) v[tt] = 3.4e38f;

#pragma unroll 2
    for (int j = 0; j < NCH; ++j) {
        float4 c = Cb[j*64 + lane];
        float dot = fmaf(c.z, Q.z, fmaf(c.y, Q.y, c.x * Q.x));
        float d = fmaf(-2.0f, dot, Q.w + c.w);   // == (qq+ss) - 2*dot, single rounding
        v[15] = fminf(v[15], d);
#pragma unroll
        for (int tt = 15; tt >= 1; --tt) {       // restore sortedness: bubble toward 0
            float lo = fminf(v[tt-1], v[tt]);
            float hi = fmaxf(v[tt-1], v[tt]);
            v[tt-1] = lo; v[tt] = hi;
        }
    }

    float T = 0.0f;
    for (int r = 0; r < 16; ++r) {               // extract global min 16 times (one entry per round)
        float g = v[0];
#pragma unroll
        for (int s = 1; s < 64; s <<= 1) g = fminf(g, __shfl_xor(g, s, 64));
        unsigned long long mk = __ballot(v[0] == g);
        int fl = __ffsll(mk) - 1;                // exactly one lane consumes (value ties resolved)
        if (lane == fl) {
#pragma unroll
            for (int tt = 0; tt < 15; ++tt) v[tt] = v[tt+1];
            v[15] = 3.4e38f;
        }
        T = g;
    }

    unsigned long long mlt = (1ull << lane) - 1ull;
    int base = q * K_;
    int cnt = 0;
    for (int j = 0; j < NCH; ++j) {              // all strictly-closer candidates (<= 15 of them)
        float4 c = Cb[j*64 + lane];
        float dot = fmaf(c.z, Q.z, fmaf(c.y, Q.y, c.x * Q.x));
        float d = fmaf(-2.0f, dot, Q.w + c.w);
        bool lt = d < T;
        unsigned long long m1 = __ballot(lt);
        if (lt) outIdx[base + cnt + __popcll(m1 & mlt)] = j*64 + lane;
        cnt += __popcll(m1);
    }
    int rem = K_ - cnt;                          // >= 1 (T itself); fill with earliest-index ties
    for (int j = 0; j < NCH && rem > 0; ++j) {
        float4 c = Cb[j*64 + lane];
        float dot = fmaf(c.z, Q.z, fmaf(c.y, Q.y, c.x * Q.x));
        float d = fmaf(-2.0f, dot, Q.w + c.w);
        bool eq = (d == T);
        unsigned long long m2 = __ballot(eq);
        int bef = __popcll(m2 & mlt);
        if (eq && bef < rem) outIdx[base + cnt + bef] = j*64 + lane;
        int take = __popcll(m2); if (take > rem) take = rem;
        cnt += take; rem -= take;
    }
}

// ---------------------------------------------------------------- layer 1: feats=[rel(3), ngh(3)] x W1[6,128], relu, max over k
__global__ __launch_bounds__(128) void layer1_kernel(const float4* __restrict__ coords4,
        const float4* __restrict__ sub4, const int* __restrict__ idx1,
        const float* __restrict__ W1, const float* __restrict__ b1,
        float* __restrict__ f1) {
    int q = blockIdx.x;
    int b = q / M_, m = q % M_;
    int c = threadIdx.x;
    __shared__ float4 ngh[K_];
    if (c < K_) ngh[c] = coords4[b*N_ + idx1[q*K_ + c]];
    __syncthreads();
    float4 Q = sub4[b*SUBP_ + m];
    float w0 = W1[c],        w1 = W1[C1_ + c],   w2 = W1[2*C1_ + c];
    float w3 = W1[3*C1_ + c], w4 = W1[4*C1_ + c], w5 = W1[5*C1_ + c];
    float bias = b1[c];
    float mx = -3.4e38f;
#pragma unroll
    for (int k = 0; k < K_; ++k) {
        float4 n = ngh[k];
        float rx = n.x - Q.x, ry = n.y - Q.y, rz = n.z - Q.z;
        float s = rx*w0; s = fmaf(ry,w1,s); s = fmaf(rz,w2,s);
        s = fmaf(n.x,w3,s); s = fmaf(n.y,w4,s); s = fmaf(n.z,w5,s);
        s += bias;
        s = fmaxf(s, 0.0f);
        mx = fmaxf(mx, s);
    }
    f1[q*C1_ + c] = mx;
}

// ---------------------------------------------------------------- layer 2: feats=[rel(3), fg(128)] x W2[131,256], relu, max over k
#define FPAD 20   // row pitch (floats): 16B-aligned rows, odd-ish banking for staging
__global__ __launch_bounds__(64) void layer2_kernel(const float4* __restrict__ sub4,
        const float* __restrict__ f1, const int* __restrict__ idx2,
        const float* __restrict__ W2, const float* __restrict__ b2,
        float* __restrict__ f2) {
    int q = blockIdx.x;
    int b = q / M_, m = q % M_;
    int t = threadIdx.x;
    __shared__ __align__(16) float feat[(3 + C1_) * FPAD];  // feat[f][k], k=0..15
    __shared__ int nidx[K_];
    float4 Q = sub4[b*SUBP_ + m];
    if (t < K_) {
        int ik = idx2[q*K_ + t];
        nidx[t] = ik;
        float4 n = sub4[b*SUBP_ + ik];
        feat[0*FPAD + t] = n.x - Q.x;
        feat[1*FPAD + t] = n.y - Q.y;
        feat[2*FPAD + t] = n.z - Q.z;
    }
    __syncthreads();
    for (int e = t; e < K_ * C1_; e += 64) {    // stage gathered f1 rows: feat[3+cc][k]
        int k = e >> 7, cc = e & 127;
        feat[(3 + cc)*FPAD + k] = f1[(b*M_ + nidx[k])*C1_ + cc];
    }
    __syncthreads();

    float acc[K_][4];
#pragma unroll
    for (int k = 0; k < K_; ++k) { acc[k][0]=0.f; acc[k][1]=0.f; acc[k][2]=0.f; acc[k][3]=0.f; }
    int c0 = t * 4;                              // 4 channels per thread, 64 threads = 256 ch
    for (int f = 0; f < 3 + C1_; ++f) {
        float4 w  = *(const float4*)(W2 + f*C2_ + c0);
        const float* row = feat + f*FPAD;
        float4 g0 = *(const float4*)(row + 0);
        float4 g1 = *(const float4*)(row + 4);
        float4 g2 = *(const float4*)(row + 8);
        float4 g3 = *(const float4*)(row + 12);
        float gk[16] = {g0.x,g0.y,g0.z,g0.w, g1.x,g1.y,g1.z,g1.w,
                        g2.x,g2.y,g2.z,g2.w, g3.x,g3.y,g3.z,g3.w};
#pragma unroll
        for (int k = 0; k < K_; ++k) {
            acc[k][0] = fmaf(gk[k], w.x, acc[k][0]);
            acc[k][1] = fmaf(gk[k], w.y, acc[k][1]);
            acc[k][2] = fmaf(gk[k], w.z, acc[k][2]);
            acc[k][3] = fmaf(gk[k], w.w, acc[k][3]);
        }
    }
    float4 bb = *(const float4*)(b2 + c0);
    float mx0 = -3.4e38f, mx1 = -3.4e38f, mx2 = -3.4e38f, mx3 = -3.4e38f;
#pragma unroll
    for (int k = 0; k < K_; ++k) {
        float h0 = fmaxf(acc[k][0] + bb.x, 0.0f);
        float h1 = fmaxf(acc[k][1] + bb.y, 0.0f);
        float h2 = fmaxf(acc[k][2] + bb.z, 0.0f);
        float h3 = fmaxf(acc[k][3] + bb.w, 0.0f);
        mx0 = fmaxf(mx0, h0); mx1 = fmaxf(mx1, h1);
        mx2 = fmaxf(mx2, h2); mx3 = fmaxf(mx3, h3);
    }
    *(float4*)(f2 + q*C2_ + c0) = make_float4(mx0, mx1, mx2, mx3);
}

// ---------------------------------------------------------------- fused adaptive max+avg pool
__global__ __launch_bounds__(256) void pool_kernel(const float* __restrict__ f2,
                                                   float* __restrict__ out) {
    int bo = blockIdx.x;
    int b = bo / OUT_, o = bo % OUT_;
    int c = threadIdx.x;
    float mx = -3.4e38f, sm = 0.0f;
#pragma unroll
    for (int w = 0; w < M_/OUT_; ++w) {
        float v = f2[(b*M_ + o*(M_/OUT_) + w)*C2_ + c];
        mx = fmaxf(mx, v);
        sm += v;
    }
    out[(b*C2_ + c)*OUT_ + o] = mx + sm / (float)(M_/OUT_);
}

// ---------------------------------------------------------------- launch
extern "C" void kernel_launch(void* const* d_in, const int* in_sizes, int n_in,
                              void* d_out, int out_size, void* d_ws, size_t ws_size,
                              hipStream_t stream) {
    const float* x  = (const float*)d_in[0];
    const float* W1 = (const float*)d_in[1];
    const float* b1 = (const float*)d_in[2];
    const float* W2 = (const float*)d_in[3];
    const float* b2 = (const float*)d_in[4];
    float* out = (float*)d_out;

    char* ws = (char*)d_ws;
    size_t off = 0;
    auto alloc = [&](size_t bytes) {
        void* p = ws + off;
        off += (bytes + 255) & ~(size_t)255;
        return p;
    };
    float4* coords4 = (float4*)alloc((size_t)B_*N_*sizeof(float4));     // 2 MB
    float4* sub4    = (float4*)alloc((size_t)B_*SUBP_*sizeof(float4));  // 256 KB
    int*    idx1    = (int*)  alloc((size_t)B_*M_*K_*sizeof(int));      // 2 MB
    int*    idx2    = (int*)  alloc((size_t)B_*M_*K_*sizeof(int));      // 2 MB
    float*  f1      = (float*)alloc((size_t)B_*M_*C1_*sizeof(float));   // 8 MB
    float*  f2      = (float*)alloc((size_t)B_*M_*C2_*sizeof(float));   // 16 MB

    prep_kernel<<<(B_*N_ + 255)/256, 256, 0, stream>>>(x, coords4, sub4);
    fps_kernel<<<B_, FPS_T, 0, stream>>>(coords4, sub4);
    knn_kernel<N_/64,    N_   ><<<B_*M_/4, 256, 0, stream>>>(coords4, sub4, idx1);
    knn_kernel<SUBP_/64, SUBP_><<<B_*M_/4, 256, 0, stream>>>(sub4,    sub4, idx2);
    layer1_kernel<<<B_*M_, 128, 0, stream>>>(coords4, sub4, idx1, W1, b1, f1);
    layer2_kernel<<<B_*M_,  64, 0, stream>>>(sub4, f1, idx2, W2, b2, f2);
    pool_kernel<<<B_*OUT_, 256, 0, stream>>>(f2, out);
}

// Round 11
// 1991.575 us; speedup vs baseline: 1.0525x; 1.0525x over previous
//
#include <hip/hip_runtime.h>

#define B_    8
#define N_    8192
#define M_    2000
#define K_    16
#define C1_   128
#define C2_   256
#define OUT_  100
#define SUBP_ 2048   // padded per-batch pitch for subsampled points (KNN2 candidates)

// ---------------------------------------------------------------- prep: coords -> float4(x,y,z,|p|^2); pad sub4 sentinels
__global__ __launch_bounds__(256) void prep_kernel(const float* __restrict__ x,
                                                   float4* __restrict__ coords4,
                                                   float4* __restrict__ sub4) {
    int i = blockIdx.x * 256 + threadIdx.x;
    if (i < B_ * N_) {
        float xx = x[i*3+0], yy = x[i*3+1], zz = x[i*3+2];
        float ss = fmaf(zz, zz, fmaf(yy, yy, xx*xx));   // ((x^2+y^2)+z^2)
        coords4[i] = make_float4(xx, yy, zz, ss);
    }
    if (i < B_ * (SUBP_ - M_)) {   // sentinel pads: huge distance, never selected
        int b = i / (SUBP_ - M_), j = i % (SUBP_ - M_);
        sub4[b*SUBP_ + M_ + j] = make_float4(1e15f, 1e15f, 1e15f, 3e30f);
    }
}

// ---------------------------------------------------------------- FPS v9 (restored verbatim — best measured: 1376us)
// v10 post-mortem: 16-way split raised FIXED per-iter cost (prune x16, heavier
// combine, 1024T barrier) more than it cut active work -> 1465us. 8-wave octant
// geometry is the fixed-vs-active optimum. v9 = Morton sort -> octant/wave,
// complement SIMD pairing, wave-bbox prune vs cached wavemax, in-loop strict->
// argmax, single u64 DPP chain, 1 barrier + parity dbuf.
#define FPS_T 512
#define FPS_P 16   // points per thread: 512*16 = 8192

__device__ __forceinline__ unsigned long long umax64(unsigned long long a, unsigned long long b) {
    return a > b ? a : b;
}

// one stage of wave-max on a u64 key via DPP on both halves (identity 0: keys are non-negative)
template<int CTRL>
__device__ __forceinline__ unsigned long long dpp_max_u64(unsigned long long v) {
    int lo = __builtin_amdgcn_update_dpp(0, (int)(unsigned)(v & 0xFFFFFFFFull), CTRL, 0xF, 0xF, true);
    int hi = __builtin_amdgcn_update_dpp(0, (int)(v >> 32),                     CTRL, 0xF, 0xF, true);
    unsigned long long o = ((unsigned long long)(unsigned)hi << 32) | (unsigned)lo;
    return umax64(v, o);
}

__device__ __forceinline__ int spread3(int v) {   // 3 bits -> bits 0,3,6
    return (v & 1) | ((v & 2) << 2) | ((v & 4) << 4);
}

__global__ __launch_bounds__(FPS_T, 1) void fps_kernel(const float4* __restrict__ coords4,
                                                       float4* __restrict__ sub4) {
    int b = blockIdx.x;
    int t = threadIdx.x;
    int w = t >> 6, lane = t & 63;
    const float4* C = coords4 + b * N_;

    __shared__ float4 Clds[N_];                              // 128 KB coords mirror (by ORIGINAL index)
    __shared__ unsigned short sidx[N_];                      // 16 KB sorted->original index map
    __shared__ unsigned int hist[512];                       // counting-sort histogram / cursors
    __shared__ __align__(16) unsigned long long wkey[2][8];  // per-wave max keys, parity double-buffered

    if (t < 512) hist[t] = 0u;
    __syncthreads();

    // ---- phase A: load coords (coalesced), mirror to LDS, Morton-cell histogram
    int cellv[FPS_P];
#pragma unroll
    for (int j = 0; j < FPS_P; ++j) {
        int i = t + j*FPS_T;
        float4 p = C[i];
        Clds[i] = p;
        int cx = (int)(p.x * 8.0f); cx = cx < 0 ? 0 : (cx > 7 ? 7 : cx);
        int cy = (int)(p.y * 8.0f); cy = cy < 0 ? 0 : (cy > 7 ? 7 : cy);
        int cz = (int)(p.z * 8.0f); cz = cz < 0 ? 0 : (cz > 7 ? 7 : cz);
        int cell = (spread3(cx) << 2) | (spread3(cy) << 1) | spread3(cz);   // 9-bit Morton
        cellv[j] = cell;
        atomicAdd(&hist[cell], 1u);
    }
    __syncthreads();

    // ---- phase B: exclusive prefix sum of hist[512] (wave 0)
    if (w == 0) {
        unsigned loc[8], tot = 0u;
#pragma unroll
        for (int c2 = 0; c2 < 8; ++c2) { loc[c2] = hist[lane*8 + c2]; tot += loc[c2]; }
        unsigned pre = tot;
#pragma unroll
        for (int d = 1; d < 64; d <<= 1) {
            unsigned o = __shfl_up(pre, d, 64);
            if (lane >= (unsigned)d) pre += o;
        }
        unsigned run = pre - tot;                            // exclusive base for this lane's 8 cells
#pragma unroll
        for (int c2 = 0; c2 < 8; ++c2) { unsigned v = loc[c2]; hist[lane*8 + c2] = run; run += v; }
    }
    __syncthreads();

    // ---- phase C: scatter original indices into Morton order
#pragma unroll
    for (int j = 0; j < FPS_P; ++j) {
        int i = t + j*FPS_T;
        unsigned pos = atomicAdd(&hist[cellv[j]], 1u);
        sidx[pos] = (unsigned short)i;
    }
    __syncthreads();

    // ---- phase D: wave w owns octant (complement pairing); lane owns 16 sorted points
    int oct = (w < 4) ? w : 11 - w;                          // SIMD pairs {w,w+4} -> opposite corners
    int sbase = oct*1024 + lane*FPS_P;
    float px_[FPS_P], py_[FPS_P], pz_[FPS_P], mind[FPS_P];
    unsigned inv_[FPS_P];
    float wx0 =  1e30f, wy0 =  1e30f, wz0 =  1e30f;
    float wx1 = -1e30f, wy1 = -1e30f, wz1 = -1e30f;
#pragma unroll
    for (int j = 0; j < FPS_P; ++j) {
        int o = (int)sidx[sbase + j];
        float4 p = Clds[o];
        px_[j] = p.x; py_[j] = p.y; pz_[j] = p.z;
        mind[j] = 1e30f;
        inv_[j] = 0xFFFFFFFFu - (unsigned)o;                 // tie -> smaller ORIGINAL index
        wx0 = fminf(wx0, p.x); wx1 = fmaxf(wx1, p.x);
        wy0 = fminf(wy0, p.y); wy1 = fmaxf(wy1, p.y);
        wz0 = fminf(wz0, p.z); wz1 = fmaxf(wz1, p.z);
    }
    // wave bbox: reduce lane bboxes across the wave (one-time)
    for (int s = 1; s < 64; s <<= 1) {
        wx0 = fminf(wx0, __shfl_xor(wx0, s, 64)); wx1 = fmaxf(wx1, __shfl_xor(wx1, s, 64));
        wy0 = fminf(wy0, __shfl_xor(wy0, s, 64)); wy1 = fmaxf(wy1, __shfl_xor(wy1, s, 64));
        wz0 = fminf(wz0, __shfl_xor(wz0, s, 64)); wz1 = fmaxf(wz1, __shfl_xor(wz1, s, 64));
    }

    float4 P0 = Clds[0];                                     // first pick = original index 0
    if (t == 0) sub4[b*SUBP_] = P0;
    float Px = P0.x, Py = P0.y, Pz = P0.z;
    unsigned long long wk = ((unsigned long long)__float_as_uint(1e30f) << 32);  // cached wave key (lane63)
    float wmaxf = 1e30f;                                     // cached wave-max mind (all lanes, via readlane)

    for (int i = 1; i < M_; ++i) {
        // wave-level prune: dmin^2(P, wavebbox) vs cached wave max (skip => bit-exact no-op)
        float qx = fminf(fmaxf(Px, wx0), wx1);
        float qy = fminf(fmaxf(Py, wy0), wy1);
        float qz = fminf(fmaxf(Pz, wz0), wz1);
        float ddx = Px - qx, ddy = Py - qy, ddz = Pz - qz;
        float dmin2 = fmaf(ddz, ddz, fmaf(ddy, ddy, ddx*ddx));
        if (dmin2 * 0.99999f < wmaxf) {                      // ACTIVE: full recompute (all lanes)
            float runmax = -3.4e38f;
            unsigned ib = 0u;
#pragma unroll
            for (int j = 0; j < FPS_P; ++j) {
                float dx = px_[j] - Px, dy = py_[j] - Py, dz = pz_[j] - Pz;
                float d = fmaf(dz, dz, fmaf(dy, dy, dx*dx)); // direct form matches reference FPS
                float m = fminf(mind[j], d);
                mind[j] = m;
                ib = (m > runmax) ? inv_[j] : ib;            // strict >: first max = smallest orig idx
                runmax = fmaxf(runmax, m);
            }
            unsigned long long best = ((unsigned long long)__float_as_uint(runmax) << 32)
                                    | (unsigned long long)ib;
            // wave max into lane 63: row_shr 1/2/4/8 then row_bcast 15/31 (all VALU)
            best = dpp_max_u64<0x111>(best);
            best = dpp_max_u64<0x112>(best);
            best = dpp_max_u64<0x114>(best);
            best = dpp_max_u64<0x118>(best);
            best = dpp_max_u64<0x142>(best);
            best = dpp_max_u64<0x143>(best);
            wk = best;
            wmaxf = __uint_as_float((unsigned)__builtin_amdgcn_readlane((int)(unsigned)(wk >> 32), 63));
        }
        if (lane == 63) wkey[i & 1][w] = wk;
        __syncthreads();
        const ulonglong2* wk2 = (const ulonglong2*)wkey[i & 1];
        ulonglong2 q0 = wk2[0], q1 = wk2[1], q2 = wk2[2], q3 = wk2[3];
        unsigned long long gk = umax64(umax64(umax64(q0.x, q0.y), umax64(q1.x, q1.y)),
                                       umax64(umax64(q2.x, q2.y), umax64(q3.x, q3.y)));
        int last = (int)(0xFFFFFFFFu - (unsigned)(gk & 0xFFFFFFFFull));
        float4 P4 = Clds[last];                              // broadcast LDS read (w = |p|^2 intact)
        Px = P4.x; Py = P4.y; Pz = P4.z;
        if (t == 0) sub4[b*SUBP_ + i] = P4;
    }
}

// ---------------------------------------------------------------- KNN: 1 wave per query, exact top-16 (set semantics)
// Pass 1: branchless lane-local sorted-16 of values only (15 CE bubble per candidate).
// Merge:  k-way merge of 64 sorted heads -> T = exact 16th smallest distance.
// Pass 2: ballot-collect indices with d<T, then earliest-index ties d==T (matches lax.top_k stability).
template<int NCH, int PITCH>
__global__ __launch_bounds__(256) void knn_kernel(const float4* __restrict__ cand,
                                                  const float4* __restrict__ qarr,
                                                  int* __restrict__ outIdx) {
    int lane = threadIdx.x & 63;
    int q = blockIdx.x * 4 + (threadIdx.x >> 6);
    int b = q / M_, m = q % M_;
    const float4* Cb = cand + b * PITCH;
    float4 Q = qarr[b * SUBP_ + m];

    float v[16];
#pragma unroll
    for (int tt = 0; tt < 16; ++tt) v[tt] = 3.4e38f;

#pragma unroll 2
    for (int j = 0; j < NCH; ++j) {
        float4 c = Cb[j*64 + lane];
        float dot = fmaf(c.z, Q.z, fmaf(c.y, Q.y, c.x * Q.x));
        float d = fmaf(-2.0f, dot, Q.w + c.w);   // == (qq+ss) - 2*dot, single rounding
        v[15] = fminf(v[15], d);
#pragma unroll
        for (int tt = 15; tt >= 1; --tt) {       // restore sortedness: bubble toward 0
            float lo = fminf(v[tt-1], v[tt]);
            float hi = fmaxf(v[tt-1], v[tt]);
            v[tt-1] = lo; v[tt] = hi;
        }
    }

    float T = 0.0f;
    for (int r = 0; r < 16; ++r) {               // extract global min 16 times (one entry per round)
        float g = v[0];
#pragma unroll
        for (int s = 1; s < 64; s <<= 1) g = fminf(g, __shfl_xor(g, s, 64));
        unsigned long long mk = __ballot(v[0] == g);
        int fl = __ffsll(mk) - 1;                // exactly one lane consumes (value ties resolved)
        if (lane == fl) {
#pragma unroll
            for (int tt = 0; tt < 15; ++tt) v[tt] = v[tt+1];
            v[15] = 3.4e38f;
        }
        T = g;
    }

    unsigned long long mlt = (1ull << lane) - 1ull;
    int base = q * K_;
    int cnt = 0;
    for (int j = 0; j < NCH; ++j) {              // all strictly-closer candidates (<= 15 of them)
        float4 c = Cb[j*64 + lane];
        float dot = fmaf(c.z, Q.z, fmaf(c.y, Q.y, c.x * Q.x));
        float d = fmaf(-2.0f, dot, Q.w + c.w);
        bool lt = d < T;
        unsigned long long m1 = __ballot(lt);
        if (lt) outIdx[base + cnt + __popcll(m1 & mlt)] = j*64 + lane;
        cnt += __popcll(m1);
    }
    int rem = K_ - cnt;                          // >= 1 (T itself); fill with earliest-index ties
    for (int j = 0; j < NCH && rem > 0; ++j) {
        float4 c = Cb[j*64 + lane];
        float dot = fmaf(c.z, Q.z, fmaf(c.y, Q.y, c.x * Q.x));
        float d = fmaf(-2.0f, dot, Q.w + c.w);
        bool eq = (d == T);
        unsigned long long m2 = __ballot(eq);
        int bef = __popcll(m2 & mlt);
        if (eq && bef < rem) outIdx[base + cnt + bef] = j*64 + lane;
        int take = __popcll(m2); if (take > rem) take = rem;
        cnt += take; rem -= take;
    }
}

// ---------------------------------------------------------------- layer 1: feats=[rel(3), ngh(3)] x W1[6,128], relu, max over k
__global__ __launch_bounds__(128) void layer1_kernel(const float4* __restrict__ coords4,
        const float4* __restrict__ sub4, const int* __restrict__ idx1,
        const float* __restrict__ W1, const float* __restrict__ b1,
        float* __restrict__ f1) {
    int q = blockIdx.x;
    int b = q / M_, m = q % M_;
    int c = threadIdx.x;
    __shared__ float4 ngh[K_];
    if (c < K_) ngh[c] = coords4[b*N_ + idx1[q*K_ + c]];
    __syncthreads();
    float4 Q = sub4[b*SUBP_ + m];
    float w0 = W1[c],        w1 = W1[C1_ + c],   w2 = W1[2*C1_ + c];
    float w3 = W1[3*C1_ + c], w4 = W1[4*C1_ + c], w5 = W1[5*C1_ + c];
    float bias = b1[c];
    float mx = -3.4e38f;
#pragma unroll
    for (int k = 0; k < K_; ++k) {
        float4 n = ngh[k];
        float rx = n.x - Q.x, ry = n.y - Q.y, rz = n.z - Q.z;
        float s = rx*w0; s = fmaf(ry,w1,s); s = fmaf(rz,w2,s);
        s = fmaf(n.x,w3,s); s = fmaf(n.y,w4,s); s = fmaf(n.z,w5,s);
        s += bias;
        s = fmaxf(s, 0.0f);
        mx = fmaxf(mx, s);
    }
    f1[q*C1_ + c] = mx;
}

// ---------------------------------------------------------------- layer 2: feats=[rel(3), fg(128)] x W2[131,256], relu, max over k
// R10: inner accumulate rewritten as float2 (__builtin_elementwise_fma) so ISel can
// emit v_pk_fma_f32 (2 FMA/inst): 32 pk-fma per feature instead of 64 scalar fma.
// Bit-exact: pk halves round identically to scalar fma; accumulation order unchanged.
#define FPAD 20   // row pitch (floats): 16B-aligned rows, odd-ish banking for staging
typedef float v2f __attribute__((ext_vector_type(2)));
__global__ __launch_bounds__(64) void layer2_kernel(const float4* __restrict__ sub4,
        const float* __restrict__ f1, const int* __restrict__ idx2,
        const float* __restrict__ W2, const float* __restrict__ b2,
        float* __restrict__ f2) {
    int q = blockIdx.x;
    int b = q / M_, m = q % M_;
    int t = threadIdx.x;
    __shared__ __align__(16) float feat[(3 + C1_) * FPAD];  // feat[f][k], k=0..15
    __shared__ int nidx[K_];
    float4 Q = sub4[b*SUBP_ + m];
    if (t < K_) {
        int ik = idx2[q*K_ + t];
        nidx[t] = ik;
        float4 n = sub4[b*SUBP_ + ik];
        feat[0*FPAD + t] = n.x - Q.x;
        feat[1*FPAD + t] = n.y - Q.y;
        feat[2*FPAD + t] = n.z - Q.z;
    }
    __syncthreads();
    for (int e = t; e < K_ * C1_; e += 64) {    // stage gathered f1 rows: feat[3+cc][k]
        int k = e >> 7, cc = e & 127;
        feat[(3 + cc)*FPAD + k] = f1[(b*M_ + nidx[k])*C1_ + cc];
    }
    __syncthreads();

    v2f acc2[K_][2];                             // [k][pair]: ch {c0,c0+1}, {c0+2,c0+3}
#pragma unroll
    for (int k = 0; k < K_; ++k) { acc2[k][0] = (v2f){0.f,0.f}; acc2[k][1] = (v2f){0.f,0.f}; }
    int c0 = t * 4;                              // 4 channels per thread, 64 threads = 256 ch
    for (int f = 0; f < 3 + C1_; ++f) {
        float4 wv = *(const float4*)(W2 + f*C2_ + c0);
        v2f w01 = (v2f){wv.x, wv.y}, w23 = (v2f){wv.z, wv.w};
        const float* row = feat + f*FPAD;
        float4 g0 = *(const float4*)(row + 0);
        float4 g1 = *(const float4*)(row + 4);
        float4 g2 = *(const float4*)(row + 8);
        float4 g3 = *(const float4*)(row + 12);
        float gk[16] = {g0.x,g0.y,g0.z,g0.w, g1.x,g1.y,g1.z,g1.w,
                        g2.x,g2.y,g2.z,g2.w, g3.x,g3.y,g3.z,g3.w};
#pragma unroll
        for (int k = 0; k < K_; ++k) {
            v2f gg = (v2f){gk[k], gk[k]};        // splat -> op_sel broadcast in v_pk_fma_f32
            acc2[k][0] = __builtin_elementwise_fma(gg, w01, acc2[k][0]);
            acc2[k][1] = __builtin_elementwise_fma(gg, w23, acc2[k][1]);
        }
    }
    float4 bb = *(const float4*)(b2 + c0);
    float mx0 = -3.4e38f, mx1 = -3.4e38f, mx2 = -3.4e38f, mx3 = -3.4e38f;
#pragma unroll
    for (int k = 0; k < K_; ++k) {
        float h0 = fmaxf(acc2[k][0].x + bb.x, 0.0f);
        float h1 = fmaxf(acc2[k][0].y + bb.y, 0.0f);
        float h2 = fmaxf(acc2[k][1].x + bb.z, 0.0f);
        float h3 = fmaxf(acc2[k][1].y + bb.w, 0.0f);
        mx0 = fmaxf(mx0, h0); mx1 = fmaxf(mx1, h1);
        mx2 = fmaxf(mx2, h2); mx3 = fmaxf(mx3, h3);
    }
    *(float4*)(f2 + q*C2_ + c0) = make_float4(mx0, mx1, mx2, mx3);
}

// ---------------------------------------------------------------- fused adaptive max+avg pool
__global__ __launch_bounds__(256) void pool_kernel(const float* __restrict__ f2,
                                                   float* __restrict__ out) {
    int bo = blockIdx.x;
    int b = bo / OUT_, o = bo % OUT_;
    int c = threadIdx.x;
    float mx = -3.4e38f, sm = 0.0f;
#pragma unroll
    for (int w = 0; w < M_/OUT_; ++w) {
        float v = f2[(b*M_ + o*(M_/OUT_) + w)*C2_ + c];
        mx = fmaxf(mx, v);
        sm += v;
    }
    out[(b*C2_ + c)*OUT_ + o] = mx + sm / (float)(M_/OUT_);
}

// ---------------------------------------------------------------- launch
extern "C" void kernel_launch(void* const* d_in, const int* in_sizes, int n_in,
                              void* d_out, int out_size, void* d_ws, size_t ws_size,
                              hipStream_t stream) {
    const float* x  = (const float*)d_in[0];
    const float* W1 = (const float*)d_in[1];
    const float* b1 = (const float*)d_in[2];
    const float* W2 = (const float*)d_in[3];
    const float* b2 = (const float*)d_in[4];
    float* out = (float*)d_out;

    char* ws = (char*)d_ws;
    size_t off = 0;
    auto alloc = [&](size_t bytes) {
        void* p = ws + off;
        off += (bytes + 255) & ~(size_t)255;
        return p;
    };
    float4* coords4 = (float4*)alloc((size_t)B_*N_*sizeof(float4));     // 2 MB
    float4* sub4    = (float4*)alloc((size_t)B_*SUBP_*sizeof(float4));  // 256 KB
    int*    idx1    = (int*)  alloc((size_t)B_*M_*K_*sizeof(int));      // 2 MB
    int*    idx2    = (int*)  alloc((size_t)B_*M_*K_*sizeof(int));      // 2 MB
    float*  f1      = (float*)alloc((size_t)B_*M_*C1_*sizeof(float));   // 8 MB
    float*  f2      = (float*)alloc((size_t)B_*M_*C2_*sizeof(float));   // 16 MB

    prep_kernel<<<(B_*N_ + 255)/256, 256, 0, stream>>>(x, coords4, sub4);
    fps_kernel<<<B_, FPS_T, 0, stream>>>(coords4, sub4);
    knn_kernel<N_/64,    N_   ><<<B_*M_/4, 256, 0, stream>>>(coords4, sub4, idx1);
    knn_kernel<SUBP_/64, SUBP_><<<B_*M_/4, 256, 0, stream>>>(sub4,    sub4, idx2);
    layer1_kernel<<<B_*M_, 128, 0, stream>>>(coords4, sub4, idx1, W1, b1, f1);
    layer2_kernel<<<B_*M_,  64, 0, stream>>>(sub4, f1, idx2, W2, b2, f2);
    pool_kernel<<<B_*OUT_, 256, 0, stream>>>(f2, out);
}